// Round 4
// baseline (231.106 us; speedup 1.0000x reference)
//
#include <hip/hip_runtime.h>
#include <math.h>

// R8: move the K=128 dot+reduction onto the MFMA pipe (MfmaUtil was 0).
// Per wave-tile of 16 edges: gather 8x dwordx4 (512B/edge, unchanged),
// 16 v_pk_mul_f16 to form h=u*v, 4x mfma_f32_16x16x32_f16 against a constant
// B-fragment holding [W_mean|W_disp|W_pi|0...] as cols 0..2. The 45-stage
// shuffle fold tree of R6 (the VALU hog: 52% busy) is deleted entirely.
// D-layout (m89-verified): col=lane&15, row=4*(lane>>4)+reg -> col lanes 0/1/2
// compute mu/disp/pi epilogues for 4 edges each and store float4.
// Pipeline: a-frags consume window -> issue next tile's 8 loads -> MFMAs ->
// epilogue. Index prefetch depth 2. VGPR ~90 under (256,4)=128 cap (R7 lesson:
// the (256,8) 64-cap spilled the window to scratch, FETCH 22->187MB).

typedef _Float16 f16x8 __attribute__((ext_vector_type(8)));
typedef float f32x4 __attribute__((ext_vector_type(4)));
typedef _Float16 h2 __attribute__((ext_vector_type(2)));
union U16 { uint4 u; f16x8 v; };
union HU { uint u; h2 h; };

// ---------- fused conversion kernel: both tables f32 -> f16 ------------------
__global__ __launch_bounds__(256) void cvt_f16_fused_kernel(
    const float4* __restrict__ srcA, int nA4,
    const float4* __restrict__ srcB, int nB4,
    uint2* __restrict__ dst)
{
    int i = blockIdx.x * blockDim.x + threadIdx.x;
    if (i >= nA4 + nB4) return;
    float4 f = (i < nA4) ? srcA[i] : srcB[i - nA4];
    HU a, b;
    a.h = h2{(_Float16)f.x, (_Float16)f.y};
    b.h = h2{(_Float16)f.z, (_Float16)f.w};
    dst[i] = make_uint2(a.u, b.u);
}

// ---------- main edge kernel: MFMA formulation -------------------------------
__global__ __launch_bounds__(256, 4) void zinb_mfma_kernel(
    const _Float16* __restrict__ uhalf,   // [n_cells, 128]
    const _Float16* __restrict__ ihalf,   // [n_genes, 128]
    const float* __restrict__ ge_factor,
    const float* __restrict__ sz_factor,
    const float* __restrict__ W_mean, const float* __restrict__ b_mean,
    const float* __restrict__ W_disp, const float* __restrict__ b_disp,
    const float* __restrict__ W_pi,   const float* __restrict__ b_pi,
    const int* __restrict__ src_idx,
    const int* __restrict__ dst_idx,
    float* __restrict__ out,              // [3E]: mu | disp | pi
    int E)
{
    const int lane = threadIdx.x & 63;
    const int col  = lane & 15;           // = A-row owner / D-column
    const int kg   = lane >> 4;           // k-group within wave
    const int w    = (blockIdx.x * blockDim.x + threadIdx.x) >> 6;
    const int nw   = (gridDim.x * blockDim.x) >> 6;
    const int ntiles = E >> 4;

    const char* ubase = (const char*)uhalf;
    const char* vbase = (const char*)ihalf;

    // constant B fragment: B[k][col], cols 0..2 = W_mean/W_disp/W_pi, rest 0.
    // lane holds B[32c + 8*kg + i][col] for chunk c, i=0..7  -> 16 VGPRs.
    f16x8 bfrag[4];
    {
        const float* Wsel = (col == 0) ? W_mean : (col == 1) ? W_disp : W_pi;
#pragma unroll
        for (int c = 0; c < 4; ++c) {
            f16x8 b;
#pragma unroll
            for (int i = 0; i < 8; ++i) {
                const float wv = Wsel[32 * c + 8 * kg + i];
                b[i] = (col < 3) ? (_Float16)wv : (_Float16)0.f;
            }
            bfrag[c] = b;
        }
    }
    const float bm = b_mean[0], bd = b_disp[0], bp = b_pi[0];

    // ---- prologue: indices + first tile's feature window -------------------
    int se_c = 0, de_c = 0, se_n = 0, de_n = 0;
    U16 u0, u1, u2, u3, v0, v1, v2, v3;
    if (w < ntiles) {
        se_c = src_idx[(w << 4) + col];
        de_c = dst_idx[(w << 4) + col];
        const unsigned ou = (unsigned)se_c * 256u + ((unsigned)kg << 4);
        const unsigned ov = (unsigned)de_c * 256u + ((unsigned)kg << 4);
        u0.u = *(const uint4*)(ubase + ou);       u1.u = *(const uint4*)(ubase + ou + 64);
        u2.u = *(const uint4*)(ubase + ou + 128); u3.u = *(const uint4*)(ubase + ou + 192);
        v0.u = *(const uint4*)(vbase + ov);       v1.u = *(const uint4*)(vbase + ov + 64);
        v2.u = *(const uint4*)(vbase + ov + 128); v3.u = *(const uint4*)(vbase + ov + 192);
        int tn = w + nw; if (tn >= ntiles) tn = w;
        se_n = src_idx[(tn << 4) + col];
        de_n = dst_idx[(tn << 4) + col];
    }

    for (int t = w; t < ntiles; t += nw) {
        // A fragments: h = u * v (f16 rounding identical to the fdot2 path)
        const f16x8 a0 = u0.v * v0.v;
        const f16x8 a1 = u1.v * v1.v;
        const f16x8 a2 = u2.v * v2.v;
        const f16x8 a3 = u3.v * v3.v;

        // issue NEXT tile's feature loads (window regs now free) — overlaps
        // with the MFMAs + epilogue below and the loop-carried latency.
        {
            const unsigned ou = (unsigned)se_n * 256u + ((unsigned)kg << 4);
            const unsigned ov = (unsigned)de_n * 256u + ((unsigned)kg << 4);
            u0.u = *(const uint4*)(ubase + ou);       u1.u = *(const uint4*)(ubase + ou + 64);
            u2.u = *(const uint4*)(ubase + ou + 128); u3.u = *(const uint4*)(ubase + ou + 192);
            v0.u = *(const uint4*)(vbase + ov);       v1.u = *(const uint4*)(vbase + ov + 64);
            v2.u = *(const uint4*)(vbase + ov + 128); v3.u = *(const uint4*)(vbase + ov + 192);
        }
        // index prefetch depth 2
        int t2 = t + 2 * nw; if (t2 >= ntiles) t2 = t;
        const int se_n2 = src_idx[(t2 << 4) + col];
        const int de_n2 = dst_idx[(t2 << 4) + col];

        // the reduction: 4 MFMAs replace 64 fdot2 + 45 fold stages
        f32x4 acc = {0.f, 0.f, 0.f, 0.f};
        acc = __builtin_amdgcn_mfma_f32_16x16x32_f16(a0, bfrag[0], acc, 0, 0, 0);
        acc = __builtin_amdgcn_mfma_f32_16x16x32_f16(a1, bfrag[1], acc, 0, 0, 0);
        acc = __builtin_amdgcn_mfma_f32_16x16x32_f16(a2, bfrag[2], acc, 0, 0, 0);
        acc = __builtin_amdgcn_mfma_f32_16x16x32_f16(a3, bfrag[3], acc, 0, 0, 0);

        // ---- epilogue: lane holds D[4*kg + j][col], j=0..3 ------------------
        const int e0   = t << 4;
        const int base = kg << 2;
        // redistribute this tile's indices: edge (base+j)'s se/de live on lane base+j
        const int s0 = __shfl(se_c, base + 0, 64);
        const int s1 = __shfl(se_c, base + 1, 64);
        const int s2 = __shfl(se_c, base + 2, 64);
        const int s3 = __shfl(se_c, base + 3, 64);
        const int g0 = __shfl(de_c, base + 0, 64);
        const int g1 = __shfl(de_c, base + 1, 64);
        const int g2 = __shfl(de_c, base + 2, 64);
        const int g3 = __shfl(de_c, base + 3, 64);

        if (col == 0) {
            // mu = szf * clamp(exp(gef * sigmoid(m + bm)) - 1)
            const float ge0 = ge_factor[g0], ge1 = ge_factor[g1],
                        ge2 = ge_factor[g2], ge3 = ge_factor[g3];
            const float sz0 = sz_factor[s0], sz1 = sz_factor[s1],
                        sz2 = sz_factor[s2], sz3 = sz_factor[s3];
            float4 o;
            o.x = sz0 * fminf(fmaxf(__expf(ge0 / (1.f + __expf(-(acc[0] + bm)))) - 1.f, 1e-5f), 1e6f);
            o.y = sz1 * fminf(fmaxf(__expf(ge1 / (1.f + __expf(-(acc[1] + bm)))) - 1.f, 1e-5f), 1e6f);
            o.z = sz2 * fminf(fmaxf(__expf(ge2 / (1.f + __expf(-(acc[2] + bm)))) - 1.f, 1e-5f), 1e6f);
            o.w = sz3 * fminf(fmaxf(__expf(ge3 / (1.f + __expf(-(acc[3] + bm)))) - 1.f, 1e-5f), 1e6f);
            *(float4*)(out + e0 + base) = o;
        } else if (col == 1) {
            // disp = clamp(softplus(gef * (d + bd)))
            const float ge0 = ge_factor[g0], ge1 = ge_factor[g1],
                        ge2 = ge_factor[g2], ge3 = ge_factor[g3];
            float4 o;
            {
                const float xd = ge0 * (acc[0] + bd);
                o.x = fminf(fmaxf(fmaxf(xd, 0.f) + __logf(1.f + __expf(-fabsf(xd))), 1e-4f), 1e4f);
            }
            {
                const float xd = ge1 * (acc[1] + bd);
                o.y = fminf(fmaxf(fmaxf(xd, 0.f) + __logf(1.f + __expf(-fabsf(xd))), 1e-4f), 1e4f);
            }
            {
                const float xd = ge2 * (acc[2] + bd);
                o.z = fminf(fmaxf(fmaxf(xd, 0.f) + __logf(1.f + __expf(-fabsf(xd))), 1e-4f), 1e4f);
            }
            {
                const float xd = ge3 * (acc[3] + bd);
                o.w = fminf(fmaxf(fmaxf(xd, 0.f) + __logf(1.f + __expf(-fabsf(xd))), 1e-4f), 1e4f);
            }
            *(float4*)(out + (size_t)E + e0 + base) = o;
        } else if (col == 2) {
            // pi = sigmoid(p + bp)
            float4 o;
            o.x = 1.f / (1.f + __expf(-(acc[0] + bp)));
            o.y = 1.f / (1.f + __expf(-(acc[1] + bp)));
            o.z = 1.f / (1.f + __expf(-(acc[2] + bp)));
            o.w = 1.f / (1.f + __expf(-(acc[3] + bp)));
            *(float4*)(out + (size_t)2 * E + e0 + base) = o;
        }

        // rotate pipeline state
        se_c = se_n; de_c = de_n; se_n = se_n2; de_n = de_n2;
    }
}

// ---------- tail kernel: last E%16 edges, scalar f32 -------------------------
__global__ void zinb_tail_kernel(
    const float* __restrict__ ufeats, const float* __restrict__ ifeats,
    const float* __restrict__ ge_factor, const float* __restrict__ sz_factor,
    const float* __restrict__ W_mean, const float* __restrict__ b_mean,
    const float* __restrict__ W_disp, const float* __restrict__ b_disp,
    const float* __restrict__ W_pi,   const float* __restrict__ b_pi,
    const int* __restrict__ src_idx, const int* __restrict__ dst_idx,
    float* __restrict__ out, int E, int start)
{
    int e = start + blockIdx.x * blockDim.x + threadIdx.x;
    if (e >= E) return;
    const int s = src_idx[e], g = dst_idx[e];
    float am = 0.f, ad = 0.f, ap = 0.f;
    for (int k = 0; k < 128; ++k) {
        float h = ufeats[(size_t)s * 128 + k] * ifeats[(size_t)g * 128 + k];
        am = fmaf(h, W_mean[k], am);
        ad = fmaf(h, W_disp[k], ad);
        ap = fmaf(h, W_pi[k],   ap);
    }
    const float gef = ge_factor[g];
    const float szf = sz_factor[s];
    const float mu_ = 1.f / (1.f + __expf(-(am + b_mean[0])));
    const float pi  = 1.f / (1.f + __expf(-(ap + b_pi[0])));
    const float xd  = gef * (ad + b_disp[0]);
    const float sp  = fmaxf(xd, 0.f) + __logf(1.f + __expf(-fabsf(xd)));
    const float disp = fminf(fmaxf(sp, 1e-4f), 1e4f);
    const float mu = szf * fminf(fmaxf(__expf(gef * mu_) - 1.f, 1e-5f), 1e6f);
    out[e] = mu; out[(size_t)E + e] = disp; out[(size_t)2 * E + e] = pi;
}

// ---------- fallback: pure-f32 kernel (ws too small / E%4 != 0) --------------
__global__ __launch_bounds__(256) void zinb_edge_f32_kernel(
    const float* __restrict__ ufeats, const float* __restrict__ ifeats,
    const float* __restrict__ ge_factor, const float* __restrict__ sz_factor,
    const float* __restrict__ W_mean, const float* __restrict__ b_mean,
    const float* __restrict__ W_disp, const float* __restrict__ b_disp,
    const float* __restrict__ W_pi,   const float* __restrict__ b_pi,
    const int* __restrict__ src_idx, const int* __restrict__ dst_idx,
    float* __restrict__ out, int E)
{
    const int r = threadIdx.x & 7;
    const int slot = (blockIdx.x * blockDim.x + threadIdx.x) >> 3;
    const int n_slots = (gridDim.x * blockDim.x) >> 3;

    float4 wm[4], wd[4], wp[4];
    {
        const float4* wm4 = (const float4*)W_mean + r;
        const float4* wd4 = (const float4*)W_disp + r;
        const float4* wp4 = (const float4*)W_pi   + r;
#pragma unroll
        for (int c = 0; c < 4; ++c) { wm[c] = wm4[c*8]; wd[c] = wd4[c*8]; wp[c] = wp4[c*8]; }
    }
    const float bm = b_mean[0], bd = b_disp[0], bp = b_pi[0];

    for (int e = slot; e < E; e += n_slots) {
        const int s = src_idx[e];
        const int g = dst_idx[e];
        const float4* u4 = (const float4*)(ufeats + (size_t)s * 128) + r;
        const float4* v4 = (const float4*)(ifeats + (size_t)g * 128) + r;
        float am = 0.f, ad = 0.f, ap = 0.f;
#pragma unroll
        for (int c = 0; c < 4; ++c) {
            float4 u = u4[c*8]; float4 v = v4[c*8];
            float px = u.x*v.x, py = u.y*v.y, pz = u.z*v.z, pw = u.w*v.w;
            am = fmaf(px, wm[c].x, am); am = fmaf(py, wm[c].y, am);
            am = fmaf(pz, wm[c].z, am); am = fmaf(pw, wm[c].w, am);
            ad = fmaf(px, wd[c].x, ad); ad = fmaf(py, wd[c].y, ad);
            ad = fmaf(pz, wd[c].z, ad); ad = fmaf(pw, wd[c].w, ad);
            ap = fmaf(px, wp[c].x, ap); ap = fmaf(py, wp[c].y, ap);
            ap = fmaf(pz, wp[c].z, ap); ap = fmaf(pw, wp[c].w, ap);
        }
#pragma unroll
        for (int off = 1; off < 8; off <<= 1) {
            am += __shfl_xor(am, off); ad += __shfl_xor(ad, off); ap += __shfl_xor(ap, off);
        }
        if (r == 0) {
            const float gef = ge_factor[g];
            const float szf = sz_factor[s];
            const float mu_ = 1.f / (1.f + __expf(-(am + bm)));
            const float pi  = 1.f / (1.f + __expf(-(ap + bp)));
            const float xd  = gef * (ad + bd);
            const float sp  = fmaxf(xd, 0.f) + __logf(1.f + __expf(-fabsf(xd)));
            const float disp = fminf(fmaxf(sp, 1e-4f), 1e4f);
            const float mu = szf * fminf(fmaxf(__expf(gef * mu_) - 1.f, 1e-5f), 1e6f);
            out[e] = mu; out[(size_t)E + e] = disp; out[(size_t)2*E + e] = pi;
        }
    }
}

extern "C" void kernel_launch(void* const* d_in, const int* in_sizes, int n_in,
                              void* d_out, int out_size, void* d_ws, size_t ws_size,
                              hipStream_t stream) {
    const float* ufeats    = (const float*)d_in[0];
    const float* ifeats    = (const float*)d_in[1];
    const float* ge_factor = (const float*)d_in[2];
    const float* sz_factor = (const float*)d_in[3];
    const float* W_mean    = (const float*)d_in[4];
    const float* b_mean    = (const float*)d_in[5];
    const float* W_disp    = (const float*)d_in[6];
    const float* b_disp    = (const float*)d_in[7];
    const float* W_pi      = (const float*)d_in[8];
    const float* b_pi      = (const float*)d_in[9];
    const int*   src_idx   = (const int*)d_in[10];
    const int*   dst_idx   = (const int*)d_in[11];
    float* out = (float*)d_out;

    const int E       = in_sizes[10];
    const int n_cells = in_sizes[0] / 128;
    const int n_genes = in_sizes[1] / 128;

    const size_t u_elems = (size_t)n_cells * 128;
    const size_t i_elems = (size_t)n_genes * 128;
    const size_t ws_needed = (u_elems + i_elems) * sizeof(_Float16);

    // MFMA path needs E%4==0 for the float4 stores into the out+E / out+2E
    // sections (alignment). Tail kernel covers E%16 edges.
    if (ws_size >= ws_needed && (E & 3) == 0) {
        _Float16* uhalf = (_Float16*)d_ws;
        _Float16* ihalf = uhalf + u_elems;

        const int un4 = (int)(u_elems / 4);
        const int in4 = (int)(i_elems / 4);
        const int n4  = un4 + in4;
        hipLaunchKernelGGL(cvt_f16_fused_kernel, dim3((n4 + 255) / 256), dim3(256), 0, stream,
                           (const float4*)ufeats, un4, (const float4*)ifeats, in4,
                           (uint2*)d_ws);

        hipLaunchKernelGGL(zinb_mfma_kernel, dim3(2048), dim3(256), 0, stream,
                           uhalf, ihalf, ge_factor, sz_factor,
                           W_mean, b_mean, W_disp, b_disp, W_pi, b_pi,
                           src_idx, dst_idx, out, E);

        const int rem = E & 15;
        if (rem) {
            hipLaunchKernelGGL(zinb_tail_kernel, dim3(1), dim3(64), 0, stream,
                               ufeats, ifeats, ge_factor, sz_factor,
                               W_mean, b_mean, W_disp, b_disp, W_pi, b_pi,
                               src_idx, dst_idx, out, E, E - rem);
        }
    } else {
        hipLaunchKernelGGL(zinb_edge_f32_kernel, dim3(2048), dim3(256), 0, stream,
                           ufeats, ifeats, ge_factor, sz_factor,
                           W_mean, b_mean, W_disp, b_disp, W_pi, b_pi,
                           src_idx, dst_idx, out, E);
    }
}

// Round 5
// 168.045 us; speedup vs baseline: 1.3753x; 1.3753x over previous
//
#include <hip/hip_runtime.h>
#include <math.h>

// R9: MFMA with R6-style coalesced gathers + LDS transpose.
// R8 lesson: MFMA A-layout forced transposed gathers -> 16 L1 line-touches/edge
// (vs 4 minimal) -> 149us. R9 keeps R6's minimal gather shape (16 lanes read one
// row's 256B contiguously; 4 lines/edge), forms h=u*v in regs, stages the h-tile
// through a per-wave private 4KB LDS region (XOR-swizzled, ~2-way conflicts =
// free), ds_read_b128 the MFMA A-fragments, 4x mfma_f32_16x16x32_f16 (HW-verified
// layout from R8, which passed), R8 epilogue verbatim. No barriers: same-wave DS
// ops execute in order (RAW through LDS is safe within a wave).
// Per-lane instr per 16 edges: ~95 vs R6's ~500 (fold tree + 192 fdot2 deleted).

typedef _Float16 f16x8 __attribute__((ext_vector_type(8)));
typedef float f32x4 __attribute__((ext_vector_type(4)));
typedef _Float16 h2 __attribute__((ext_vector_type(2)));
union U16 { uint4 u; f16x8 v; };
union HU { uint u; h2 h; };

// ---------- fused conversion kernel: both tables f32 -> f16 ------------------
__global__ __launch_bounds__(256) void cvt_f16_fused_kernel(
    const float4* __restrict__ srcA, int nA4,
    const float4* __restrict__ srcB, int nB4,
    uint2* __restrict__ dst)
{
    int i = blockIdx.x * blockDim.x + threadIdx.x;
    if (i >= nA4 + nB4) return;
    float4 f = (i < nA4) ? srcA[i] : srcB[i - nA4];
    HU a, b;
    a.h = h2{(_Float16)f.x, (_Float16)f.y};
    b.h = h2{(_Float16)f.z, (_Float16)f.w};
    dst[i] = make_uint2(a.u, b.u);
}

// ---------- main edge kernel: coalesced-gather MFMA --------------------------
__global__ __launch_bounds__(256, 4) void zinb_mfma_lds_kernel(
    const _Float16* __restrict__ uhalf,   // [n_cells, 128]
    const _Float16* __restrict__ ihalf,   // [n_genes, 128]
    const float* __restrict__ ge_factor,
    const float* __restrict__ sz_factor,
    const float* __restrict__ W_mean, const float* __restrict__ b_mean,
    const float* __restrict__ W_disp, const float* __restrict__ b_disp,
    const float* __restrict__ W_pi,   const float* __restrict__ b_pi,
    const int* __restrict__ src_idx,
    const int* __restrict__ dst_idx,
    float* __restrict__ out,              // [3E]: mu | disp | pi
    int E)
{
    const int tid  = threadIdx.x;
    const int lane = tid & 63;
    const int col  = lane & 15;           // edge-in-tile / A-row / D-column
    const int kg   = lane >> 4;
    const int w    = (blockIdx.x * blockDim.x + tid) >> 6;
    const int nw   = (gridDim.x * blockDim.x) >> 6;
    const int ntiles = E >> 4;

    // per-wave private h-tile: 16 edges x 128 f16 = 4KB; no cross-wave sharing,
    // no barriers (same-wave DS ops are processed in order by the LDS unit).
    __shared__ __align__(16) _Float16 hsm[4][2048];
    char* const lds = (char*)hsm[tid >> 6];

    const char* const ubase = (const char*)uhalf;
    const char* const vbase = (const char*)ihalf;

    // constant B fragment: B[k][col], cols 0..2 = W_mean/W_disp/W_pi, rest 0
    f16x8 bfrag[4];
    {
        const float* Wsel = (col == 0) ? W_mean : (col == 1) ? W_disp : W_pi;
#pragma unroll
        for (int c = 0; c < 4; ++c) {
            f16x8 b;
#pragma unroll
            for (int i = 0; i < 8; ++i) {
                const float wv = Wsel[32 * c + 8 * kg + i];
                b[i] = (col < 3) ? (_Float16)wv : (_Float16)0.f;
            }
            bfrag[c] = b;
        }
    }
    const float bm = b_mean[0], bd = b_disp[0], bp = b_pi[0];

    // swizzled LDS byte offsets (loop-invariant). logical byte X of row R lives
    // at physical R*256 + (X ^ ((R&7)<<4)); 16B granularity preserved.
    int wofs[4], rofs[4];
#pragma unroll
    for (int j = 0; j < 4; ++j) {
        const int row = kg + 4 * j;       // staging: lane writes rows kg+4j, chunk col
        wofs[j] = row * 256 + ((col * 16) ^ ((row & 7) << 4));
    }
#pragma unroll
    for (int c = 0; c < 4; ++c)           // A-frag: row col, k-chunk c (elems 32c+8kg+i)
        rofs[c] = col * 256 + (((c << 6) + (kg << 4)) ^ ((col & 7) << 4));

    // ---- prologue: indices + stage tile w's feature rows into registers -----
    int se_c = 0, de_c = 0, se_n = 0, de_n = 0;
    U16 uR[4], vR[4];
    if (w < ntiles) {
        se_c = src_idx[(w << 4) + col];
        de_c = dst_idx[(w << 4) + col];
#pragma unroll
        for (int j = 0; j < 4; ++j) {
            const int ur = __shfl(se_c, kg + 4 * j, 64);
            const int vr = __shfl(de_c, kg + 4 * j, 64);
            uR[j].u = *(const uint4*)(ubase + (unsigned)ur * 256u + (unsigned)col * 16u);
            vR[j].u = *(const uint4*)(vbase + (unsigned)vr * 256u + (unsigned)col * 16u);
        }
        int tn = w + nw; if (tn >= ntiles) tn = w;
        se_n = src_idx[(tn << 4) + col];
        de_n = dst_idx[(tn << 4) + col];
    }

    for (int t = w; t < ntiles; t += nw) {
        // 1) h = u*v -> LDS (tile t); coalesced rows become MFMA-readable tile
#pragma unroll
        for (int j = 0; j < 4; ++j) {
            U16 h; h.v = uR[j].v * vR[j].v;
            *(uint4*)(lds + wofs[j]) = h.u;
        }

        // 2) next tile's row ids + coalesced global loads (hidden under MFMA+epi)
#pragma unroll
        for (int j = 0; j < 4; ++j) {
            const int ur = __shfl(se_n, kg + 4 * j, 64);
            const int vr = __shfl(de_n, kg + 4 * j, 64);
            uR[j].u = *(const uint4*)(ubase + (unsigned)ur * 256u + (unsigned)col * 16u);
            vR[j].u = *(const uint4*)(vbase + (unsigned)vr * 256u + (unsigned)col * 16u);
        }

        // 3) index prefetch depth 2
        int t2 = t + 2 * nw; if (t2 >= ntiles) t2 = t;
        const int se_n2 = src_idx[(t2 << 4) + col];
        const int de_n2 = dst_idx[(t2 << 4) + col];

        // 4) A fragments from LDS (DS in-order guarantees RAW after step 1)
        U16 a0, a1, a2, a3;
        a0.u = *(const uint4*)(lds + rofs[0]);
        a1.u = *(const uint4*)(lds + rofs[1]);
        a2.u = *(const uint4*)(lds + rofs[2]);
        a3.u = *(const uint4*)(lds + rofs[3]);

        // 5) the reduction on the matrix pipe
        f32x4 acc = {0.f, 0.f, 0.f, 0.f};
        acc = __builtin_amdgcn_mfma_f32_16x16x32_f16(a0.v, bfrag[0], acc, 0, 0, 0);
        acc = __builtin_amdgcn_mfma_f32_16x16x32_f16(a1.v, bfrag[1], acc, 0, 0, 0);
        acc = __builtin_amdgcn_mfma_f32_16x16x32_f16(a2.v, bfrag[2], acc, 0, 0, 0);
        acc = __builtin_amdgcn_mfma_f32_16x16x32_f16(a3.v, bfrag[3], acc, 0, 0, 0);

        // ---- epilogue (verbatim from R8, HW-verified): lane holds D[4kg+j][col]
        const int e0   = t << 4;
        const int base = kg << 2;
        const int s0 = __shfl(se_c, base + 0, 64);
        const int s1 = __shfl(se_c, base + 1, 64);
        const int s2 = __shfl(se_c, base + 2, 64);
        const int s3 = __shfl(se_c, base + 3, 64);
        const int g0 = __shfl(de_c, base + 0, 64);
        const int g1 = __shfl(de_c, base + 1, 64);
        const int g2 = __shfl(de_c, base + 2, 64);
        const int g3 = __shfl(de_c, base + 3, 64);

        if (col == 0) {
            const float ge0 = ge_factor[g0], ge1 = ge_factor[g1],
                        ge2 = ge_factor[g2], ge3 = ge_factor[g3];
            const float sz0 = sz_factor[s0], sz1 = sz_factor[s1],
                        sz2 = sz_factor[s2], sz3 = sz_factor[s3];
            float4 o;
            o.x = sz0 * fminf(fmaxf(__expf(ge0 / (1.f + __expf(-(acc[0] + bm)))) - 1.f, 1e-5f), 1e6f);
            o.y = sz1 * fminf(fmaxf(__expf(ge1 / (1.f + __expf(-(acc[1] + bm)))) - 1.f, 1e-5f), 1e6f);
            o.z = sz2 * fminf(fmaxf(__expf(ge2 / (1.f + __expf(-(acc[2] + bm)))) - 1.f, 1e-5f), 1e6f);
            o.w = sz3 * fminf(fmaxf(__expf(ge3 / (1.f + __expf(-(acc[3] + bm)))) - 1.f, 1e-5f), 1e6f);
            *(float4*)(out + e0 + base) = o;
        } else if (col == 1) {
            const float ge0 = ge_factor[g0], ge1 = ge_factor[g1],
                        ge2 = ge_factor[g2], ge3 = ge_factor[g3];
            float4 o;
            {
                const float xd = ge0 * (acc[0] + bd);
                o.x = fminf(fmaxf(fmaxf(xd, 0.f) + __logf(1.f + __expf(-fabsf(xd))), 1e-4f), 1e4f);
            }
            {
                const float xd = ge1 * (acc[1] + bd);
                o.y = fminf(fmaxf(fmaxf(xd, 0.f) + __logf(1.f + __expf(-fabsf(xd))), 1e-4f), 1e4f);
            }
            {
                const float xd = ge2 * (acc[2] + bd);
                o.z = fminf(fmaxf(fmaxf(xd, 0.f) + __logf(1.f + __expf(-fabsf(xd))), 1e-4f), 1e4f);
            }
            {
                const float xd = ge3 * (acc[3] + bd);
                o.w = fminf(fmaxf(fmaxf(xd, 0.f) + __logf(1.f + __expf(-fabsf(xd))), 1e-4f), 1e4f);
            }
            *(float4*)(out + (size_t)E + e0 + base) = o;
        } else if (col == 2) {
            float4 o;
            o.x = 1.f / (1.f + __expf(-(acc[0] + bp)));
            o.y = 1.f / (1.f + __expf(-(acc[1] + bp)));
            o.z = 1.f / (1.f + __expf(-(acc[2] + bp)));
            o.w = 1.f / (1.f + __expf(-(acc[3] + bp)));
            *(float4*)(out + (size_t)2 * E + e0 + base) = o;
        }

        // rotate pipeline state
        se_c = se_n; de_c = de_n; se_n = se_n2; de_n = de_n2;
    }
}

// ---------- tail kernel: last E%16 edges, scalar f32 -------------------------
__global__ void zinb_tail_kernel(
    const float* __restrict__ ufeats, const float* __restrict__ ifeats,
    const float* __restrict__ ge_factor, const float* __restrict__ sz_factor,
    const float* __restrict__ W_mean, const float* __restrict__ b_mean,
    const float* __restrict__ W_disp, const float* __restrict__ b_disp,
    const float* __restrict__ W_pi,   const float* __restrict__ b_pi,
    const int* __restrict__ src_idx, const int* __restrict__ dst_idx,
    float* __restrict__ out, int E, int start)
{
    int e = start + blockIdx.x * blockDim.x + threadIdx.x;
    if (e >= E) return;
    const int s = src_idx[e], g = dst_idx[e];
    float am = 0.f, ad = 0.f, ap = 0.f;
    for (int k = 0; k < 128; ++k) {
        float h = ufeats[(size_t)s * 128 + k] * ifeats[(size_t)g * 128 + k];
        am = fmaf(h, W_mean[k], am);
        ad = fmaf(h, W_disp[k], ad);
        ap = fmaf(h, W_pi[k],   ap);
    }
    const float gef = ge_factor[g];
    const float szf = sz_factor[s];
    const float mu_ = 1.f / (1.f + __expf(-(am + b_mean[0])));
    const float pi  = 1.f / (1.f + __expf(-(ap + b_pi[0])));
    const float xd  = gef * (ad + b_disp[0]);
    const float sp  = fmaxf(xd, 0.f) + __logf(1.f + __expf(-fabsf(xd)));
    const float disp = fminf(fmaxf(sp, 1e-4f), 1e4f);
    const float mu = szf * fminf(fmaxf(__expf(gef * mu_) - 1.f, 1e-5f), 1e6f);
    out[e] = mu; out[(size_t)E + e] = disp; out[(size_t)2 * E + e] = pi;
}

// ---------- fallback: pure-f32 kernel (ws too small / E%4 != 0) --------------
__global__ __launch_bounds__(256) void zinb_edge_f32_kernel(
    const float* __restrict__ ufeats, const float* __restrict__ ifeats,
    const float* __restrict__ ge_factor, const float* __restrict__ sz_factor,
    const float* __restrict__ W_mean, const float* __restrict__ b_mean,
    const float* __restrict__ W_disp, const float* __restrict__ b_disp,
    const float* __restrict__ W_pi,   const float* __restrict__ b_pi,
    const int* __restrict__ src_idx, const int* __restrict__ dst_idx,
    float* __restrict__ out, int E)
{
    const int r = threadIdx.x & 7;
    const int slot = (blockIdx.x * blockDim.x + threadIdx.x) >> 3;
    const int n_slots = (gridDim.x * blockDim.x) >> 3;

    float4 wm[4], wd[4], wp[4];
    {
        const float4* wm4 = (const float4*)W_mean + r;
        const float4* wd4 = (const float4*)W_disp + r;
        const float4* wp4 = (const float4*)W_pi   + r;
#pragma unroll
        for (int c = 0; c < 4; ++c) { wm[c] = wm4[c*8]; wd[c] = wd4[c*8]; wp[c] = wp4[c*8]; }
    }
    const float bm = b_mean[0], bd = b_disp[0], bp = b_pi[0];

    for (int e = slot; e < E; e += n_slots) {
        const int s = src_idx[e];
        const int g = dst_idx[e];
        const float4* u4 = (const float4*)(ufeats + (size_t)s * 128) + r;
        const float4* v4 = (const float4*)(ifeats + (size_t)g * 128) + r;
        float am = 0.f, ad = 0.f, ap = 0.f;
#pragma unroll
        for (int c = 0; c < 4; ++c) {
            float4 u = u4[c*8]; float4 v = v4[c*8];
            float px = u.x*v.x, py = u.y*v.y, pz = u.z*v.z, pw = u.w*v.w;
            am = fmaf(px, wm[c].x, am); am = fmaf(py, wm[c].y, am);
            am = fmaf(pz, wm[c].z, am); am = fmaf(pw, wm[c].w, am);
            ad = fmaf(px, wd[c].x, ad); ad = fmaf(py, wd[c].y, ad);
            ad = fmaf(pz, wd[c].z, ad); ad = fmaf(pw, wd[c].w, ad);
            ap = fmaf(px, wp[c].x, ap); ap = fmaf(py, wp[c].y, ap);
            ap = fmaf(pz, wp[c].z, ap); ap = fmaf(pw, wp[c].w, ap);
        }
#pragma unroll
        for (int off = 1; off < 8; off <<= 1) {
            am += __shfl_xor(am, off); ad += __shfl_xor(ad, off); ap += __shfl_xor(ap, off);
        }
        if (r == 0) {
            const float gef = ge_factor[g];
            const float szf = sz_factor[s];
            const float mu_ = 1.f / (1.f + __expf(-(am + bm)));
            const float pi  = 1.f / (1.f + __expf(-(ap + bp)));
            const float xd  = gef * (ad + bd);
            const float sp  = fmaxf(xd, 0.f) + __logf(1.f + __expf(-fabsf(xd)));
            const float disp = fminf(fmaxf(sp, 1e-4f), 1e4f);
            const float mu = szf * fminf(fmaxf(__expf(gef * mu_) - 1.f, 1e-5f), 1e6f);
            out[e] = mu; out[(size_t)E + e] = disp; out[(size_t)2*E + e] = pi;
        }
    }
}

extern "C" void kernel_launch(void* const* d_in, const int* in_sizes, int n_in,
                              void* d_out, int out_size, void* d_ws, size_t ws_size,
                              hipStream_t stream) {
    const float* ufeats    = (const float*)d_in[0];
    const float* ifeats    = (const float*)d_in[1];
    const float* ge_factor = (const float*)d_in[2];
    const float* sz_factor = (const float*)d_in[3];
    const float* W_mean    = (const float*)d_in[4];
    const float* b_mean    = (const float*)d_in[5];
    const float* W_disp    = (const float*)d_in[6];
    const float* b_disp    = (const float*)d_in[7];
    const float* W_pi      = (const float*)d_in[8];
    const float* b_pi      = (const float*)d_in[9];
    const int*   src_idx   = (const int*)d_in[10];
    const int*   dst_idx   = (const int*)d_in[11];
    float* out = (float*)d_out;

    const int E       = in_sizes[10];
    const int n_cells = in_sizes[0] / 128;
    const int n_genes = in_sizes[1] / 128;

    const size_t u_elems = (size_t)n_cells * 128;
    const size_t i_elems = (size_t)n_genes * 128;
    const size_t ws_needed = (u_elems + i_elems) * sizeof(_Float16);

    if (ws_size >= ws_needed && (E & 3) == 0) {
        _Float16* uhalf = (_Float16*)d_ws;
        _Float16* ihalf = uhalf + u_elems;

        const int un4 = (int)(u_elems / 4);
        const int in4 = (int)(i_elems / 4);
        const int n4  = un4 + in4;
        hipLaunchKernelGGL(cvt_f16_fused_kernel, dim3((n4 + 255) / 256), dim3(256), 0, stream,
                           (const float4*)ufeats, un4, (const float4*)ifeats, in4,
                           (uint2*)d_ws);

        hipLaunchKernelGGL(zinb_mfma_lds_kernel, dim3(2048), dim3(256), 0, stream,
                           uhalf, ihalf, ge_factor, sz_factor,
                           W_mean, b_mean, W_disp, b_disp, W_pi, b_pi,
                           src_idx, dst_idx, out, E);

        const int rem = E & 15;
        if (rem) {
            hipLaunchKernelGGL(zinb_tail_kernel, dim3(1), dim3(64), 0, stream,
                               ufeats, ifeats, ge_factor, sz_factor,
                               W_mean, b_mean, W_disp, b_disp, W_pi, b_pi,
                               src_idx, dst_idx, out, E, E - rem);
        }
    } else {
        hipLaunchKernelGGL(zinb_edge_f32_kernel, dim3(2048), dim3(256), 0, stream,
                           ufeats, ifeats, ge_factor, sz_factor,
                           W_mean, b_mean, W_disp, b_disp, W_pi, b_pi,
                           src_idx, dst_idx, out, E);
    }
}

// Round 6
// 143.128 us; speedup vs baseline: 1.6147x; 1.1741x over previous
//
#include <hip/hip_runtime.h>
#include <math.h>

// R10: amortize the epilogue. R9 was VALU-bound (75% busy) — its divergent
// 3-way epilogue ran every 16 edges (~4.4 slots/edge vs R6's 0.4). R10 keeps
// R9's HW-verified pieces (coalesced 4-line/edge gathers, swizzled LDS h-tile,
// MFMA A/B/D layouts) but processes 4 sub-tiles = 64 edges per wave-iteration:
// each sub-tile's acc is stashed to a per-wave LDS osm[192] (one masked
// ds_write_b128), then ONE full-wave epilogue (each lane owns edge e0+lane;
// 3 stride-1 ds_read_b32 = 2-way free; branch-free; coalesced stores).
// VALU ~2.3 slots/edge vs R9 7.9 / R6 5.1. Same-wave DS ops are in-order, so
// no barriers are needed (wave-private LDS regions).

typedef _Float16 f16x8 __attribute__((ext_vector_type(8)));
typedef float f32x4 __attribute__((ext_vector_type(4)));
typedef _Float16 h2 __attribute__((ext_vector_type(2)));
union U16 { uint4 u; f16x8 v; };
union HU { uint u; h2 h; };

// ---------- fused conversion kernel: both tables f32 -> f16 ------------------
__global__ __launch_bounds__(256) void cvt_f16_fused_kernel(
    const float4* __restrict__ srcA, int nA4,
    const float4* __restrict__ srcB, int nB4,
    uint2* __restrict__ dst)
{
    int i = blockIdx.x * blockDim.x + threadIdx.x;
    if (i >= nA4 + nB4) return;
    float4 f = (i < nA4) ? srcA[i] : srcB[i - nA4];
    HU a, b;
    a.h = h2{(_Float16)f.x, (_Float16)f.y};
    b.h = h2{(_Float16)f.z, (_Float16)f.w};
    dst[i] = make_uint2(a.u, b.u);
}

// stage sub-tile S's u/v rows (coalesced: 16 lanes read one row's 256B)
#define STAGE(S, SEV, DEV) {                                                  \
    _Pragma("unroll")                                                         \
    for (int j = 0; j < 4; ++j) {                                             \
        const int ur = __shfl((SEV), 16 * (S) + 4 * kg + j, 64);              \
        const int vr = __shfl((DEV), 16 * (S) + 4 * kg + j, 64);              \
        uR[j].u = *(const uint4*)(ubase + (unsigned)ur * 256u + col16);       \
        vR[j].u = *(const uint4*)(vbase + (unsigned)vr * 256u + col16);       \
    } }

// consume sub-tile S: h=u*v -> LDS, stage next (hidden), A-frags, 4 MFMA, stash
#define TILE(S, STAGE_STMT) {                                                 \
    U16 hh0, hh1, hh2, hh3;                                                   \
    hh0.v = uR[0].v * vR[0].v; hh1.v = uR[1].v * vR[1].v;                     \
    hh2.v = uR[2].v * vR[2].v; hh3.v = uR[3].v * vR[3].v;                     \
    *(uint4*)(lds + wofs[0]) = hh0.u; *(uint4*)(lds + wofs[1]) = hh1.u;       \
    *(uint4*)(lds + wofs[2]) = hh2.u; *(uint4*)(lds + wofs[3]) = hh3.u;       \
    STAGE_STMT;                                                               \
    U16 a0, a1, a2, a3;                                                       \
    a0.u = *(const uint4*)(lds + rofs[0]);                                    \
    a1.u = *(const uint4*)(lds + rofs[1]);                                    \
    a2.u = *(const uint4*)(lds + rofs[2]);                                    \
    a3.u = *(const uint4*)(lds + rofs[3]);                                    \
    f32x4 acc = {0.f, 0.f, 0.f, 0.f};                                         \
    acc = __builtin_amdgcn_mfma_f32_16x16x32_f16(a0.v, bfrag[0], acc, 0, 0, 0);\
    acc = __builtin_amdgcn_mfma_f32_16x16x32_f16(a1.v, bfrag[1], acc, 0, 0, 0);\
    acc = __builtin_amdgcn_mfma_f32_16x16x32_f16(a2.v, bfrag[2], acc, 0, 0, 0);\
    acc = __builtin_amdgcn_mfma_f32_16x16x32_f16(a3.v, bfrag[3], acc, 0, 0, 0);\
    if (col < 3) *(f32x4*)((char*)ols + col * 256 + (S) * 64 + kg * 16) = acc;\
    }

// ---------- main edge kernel: 64 edges / wave-iteration ----------------------
__global__ __launch_bounds__(256, 4) void zinb_mfma64_kernel(
    const _Float16* __restrict__ uhalf,   // [n_cells, 128]
    const _Float16* __restrict__ ihalf,   // [n_genes, 128]
    const float* __restrict__ ge_factor,
    const float* __restrict__ sz_factor,
    const float* __restrict__ W_mean, const float* __restrict__ b_mean,
    const float* __restrict__ W_disp, const float* __restrict__ b_disp,
    const float* __restrict__ W_pi,   const float* __restrict__ b_pi,
    const int* __restrict__ src_idx,
    const int* __restrict__ dst_idx,
    float* __restrict__ out,              // [3E]: mu | disp | pi
    int E)
{
    const int tid  = threadIdx.x;
    const int lane = tid & 63;
    const int col  = lane & 15;           // A-row owner / D-column
    const int kg   = lane >> 4;
    const unsigned col16 = (unsigned)col * 16u;
    const int w    = (blockIdx.x * blockDim.x + tid) >> 6;
    const int nw   = (gridDim.x * blockDim.x) >> 6;
    const int NT   = E >> 6;              // 64-edge macro tiles

    // per-wave private LDS: 4KB h-tile + 768B output-staging (m|d|p)[64]
    __shared__ __align__(16) _Float16 hsm[4][2048];
    __shared__ __align__(16) float    osm[4][192];
    char*  const lds = (char*)hsm[tid >> 6];
    float* const ols = osm[tid >> 6];

    const char* const ubase = (const char*)uhalf;
    const char* const vbase = (const char*)ihalf;

    // constant B fragment: B[k][col], cols 0..2 = W_mean/W_disp/W_pi, rest 0
    f16x8 bfrag[4];
    {
        const float* Wsel = (col == 0) ? W_mean : (col == 1) ? W_disp : W_pi;
#pragma unroll
        for (int c = 0; c < 4; ++c) {
            f16x8 b;
#pragma unroll
            for (int i = 0; i < 8; ++i) {
                const float wv = Wsel[32 * c + 8 * kg + i];
                b[i] = (col < 3) ? (_Float16)wv : (_Float16)0.f;
            }
            bfrag[c] = b;
        }
    }
    const float bm = b_mean[0], bd = b_disp[0], bp = b_pi[0];

    // swizzled LDS offsets (loop-invariant): logical byte X of row R lives at
    // R*256 + (X ^ ((R&7)<<4)). Writes: lane owns row 4kg+j, chunk col.
    int wofs[4], rofs[4];
#pragma unroll
    for (int j = 0; j < 4; ++j) {
        const int row = 4 * kg + j;
        wofs[j] = row * 256 + ((col * 16) ^ ((row & 7) << 4));
    }
#pragma unroll
    for (int c = 0; c < 4; ++c)   // A-frag: row col, bytes (c<<6)+(kg<<4)
        rofs[c] = col * 256 + (((c << 6) + (kg << 4)) ^ ((col & 7) << 4));

    // ---- prologue: own indices for iter w and w+nw; stage sub-tile 0 --------
    int se_c = 0, de_c = 0, se_n = 0, de_n = 0;
    U16 uR[4], vR[4];
    if (w < NT) {
        se_c = src_idx[(w << 6) + lane];
        de_c = dst_idx[(w << 6) + lane];
        int tn = w + nw; if (tn >= NT) tn = w;
        se_n = src_idx[(tn << 6) + lane];
        de_n = dst_idx[(tn << 6) + lane];
        STAGE(0, se_c, de_c)
    }

    for (int t = w; t < NT; t += nw) {
        // index prefetch depth 2
        int t2 = t + 2 * nw; if (t2 >= NT) t2 = t;
        const int se_n2 = src_idx[(t2 << 6) + lane];
        const int de_n2 = dst_idx[(t2 << 6) + lane];

        TILE(0, STAGE(1, se_c, de_c))
        TILE(1, STAGE(2, se_c, de_c))
        TILE(2, STAGE(3, se_c, de_c))
        TILE(3, STAGE(0, se_n, de_n))     // next iteration's sub-tile 0

        // ---- full-wave epilogue: lane owns edge e0+lane ---------------------
        const int e0 = t << 6;
        const float m  = ols[lane];
        const float dd = ols[64 + lane];
        const float pp = ols[128 + lane];
        const float gef = ge_factor[de_c];
        const float szf = sz_factor[se_c];

        const float mu_ = 1.f / (1.f + __expf(-(m + bm)));
        const float pi  = 1.f / (1.f + __expf(-(pp + bp)));
        const float xd  = gef * (dd + bd);
        const float sp  = fmaxf(xd, 0.f) + __logf(1.f + __expf(-fabsf(xd)));
        const float disp = fminf(fmaxf(sp, 1e-4f), 1e4f);
        const float mu = szf * fminf(fmaxf(__expf(gef * mu_) - 1.f, 1e-5f), 1e6f);

        const int e = e0 + lane;
        out[e]                 = mu;
        out[(size_t)E + e]     = disp;
        out[(size_t)2 * E + e] = pi;

        // rotate pipeline state
        se_c = se_n; de_c = de_n; se_n = se_n2; de_n = de_n2;
    }
}

// ---------- tail kernel: last E%64 edges, scalar f32 -------------------------
__global__ void zinb_tail_kernel(
    const float* __restrict__ ufeats, const float* __restrict__ ifeats,
    const float* __restrict__ ge_factor, const float* __restrict__ sz_factor,
    const float* __restrict__ W_mean, const float* __restrict__ b_mean,
    const float* __restrict__ W_disp, const float* __restrict__ b_disp,
    const float* __restrict__ W_pi,   const float* __restrict__ b_pi,
    const int* __restrict__ src_idx, const int* __restrict__ dst_idx,
    float* __restrict__ out, int E, int start)
{
    int e = start + blockIdx.x * blockDim.x + threadIdx.x;
    if (e >= E) return;
    const int s = src_idx[e], g = dst_idx[e];
    float am = 0.f, ad = 0.f, ap = 0.f;
    for (int k = 0; k < 128; ++k) {
        float h = ufeats[(size_t)s * 128 + k] * ifeats[(size_t)g * 128 + k];
        am = fmaf(h, W_mean[k], am);
        ad = fmaf(h, W_disp[k], ad);
        ap = fmaf(h, W_pi[k],   ap);
    }
    const float gef = ge_factor[g];
    const float szf = sz_factor[s];
    const float mu_ = 1.f / (1.f + __expf(-(am + b_mean[0])));
    const float pi  = 1.f / (1.f + __expf(-(ap + b_pi[0])));
    const float xd  = gef * (ad + b_disp[0]);
    const float sp  = fmaxf(xd, 0.f) + __logf(1.f + __expf(-fabsf(xd)));
    const float disp = fminf(fmaxf(sp, 1e-4f), 1e4f);
    const float mu = szf * fminf(fmaxf(__expf(gef * mu_) - 1.f, 1e-5f), 1e6f);
    out[e] = mu; out[(size_t)E + e] = disp; out[(size_t)2 * E + e] = pi;
}

// ---------- fallback: pure-f32 kernel (ws too small) -------------------------
__global__ __launch_bounds__(256) void zinb_edge_f32_kernel(
    const float* __restrict__ ufeats, const float* __restrict__ ifeats,
    const float* __restrict__ ge_factor, const float* __restrict__ sz_factor,
    const float* __restrict__ W_mean, const float* __restrict__ b_mean,
    const float* __restrict__ W_disp, const float* __restrict__ b_disp,
    const float* __restrict__ W_pi,   const float* __restrict__ b_pi,
    const int* __restrict__ src_idx, const int* __restrict__ dst_idx,
    float* __restrict__ out, int E)
{
    const int r = threadIdx.x & 7;
    const int slot = (blockIdx.x * blockDim.x + threadIdx.x) >> 3;
    const int n_slots = (gridDim.x * blockDim.x) >> 3;

    float4 wm[4], wd[4], wp[4];
    {
        const float4* wm4 = (const float4*)W_mean + r;
        const float4* wd4 = (const float4*)W_disp + r;
        const float4* wp4 = (const float4*)W_pi   + r;
#pragma unroll
        for (int c = 0; c < 4; ++c) { wm[c] = wm4[c*8]; wd[c] = wd4[c*8]; wp[c] = wp4[c*8]; }
    }
    const float bm = b_mean[0], bd = b_disp[0], bp = b_pi[0];

    for (int e = slot; e < E; e += n_slots) {
        const int s = src_idx[e];
        const int g = dst_idx[e];
        const float4* u4 = (const float4*)(ufeats + (size_t)s * 128) + r;
        const float4* v4 = (const float4*)(ifeats + (size_t)g * 128) + r;
        float am = 0.f, ad = 0.f, ap = 0.f;
#pragma unroll
        for (int c = 0; c < 4; ++c) {
            float4 u = u4[c*8]; float4 v = v4[c*8];
            float px = u.x*v.x, py = u.y*v.y, pz = u.z*v.z, pw = u.w*v.w;
            am = fmaf(px, wm[c].x, am); am = fmaf(py, wm[c].y, am);
            am = fmaf(pz, wm[c].z, am); am = fmaf(pw, wm[c].w, am);
            ad = fmaf(px, wd[c].x, ad); ad = fmaf(py, wd[c].y, ad);
            ad = fmaf(pz, wd[c].z, ad); ad = fmaf(pw, wd[c].w, ad);
            ap = fmaf(px, wp[c].x, ap); ap = fmaf(py, wp[c].y, ap);
            ap = fmaf(pw, wp[c].w, ap); ap = fmaf(pz, wp[c].z, ap);
        }
#pragma unroll
        for (int off = 1; off < 8; off <<= 1) {
            am += __shfl_xor(am, off); ad += __shfl_xor(ad, off); ap += __shfl_xor(ap, off);
        }
        if (r == 0) {
            const float gef = ge_factor[g];
            const float szf = sz_factor[s];
            const float mu_ = 1.f / (1.f + __expf(-(am + bm)));
            const float pi  = 1.f / (1.f + __expf(-(ap + bp)));
            const float xd  = gef * (ad + bd);
            const float sp  = fmaxf(xd, 0.f) + __logf(1.f + __expf(-fabsf(xd)));
            const float disp = fminf(fmaxf(sp, 1e-4f), 1e4f);
            const float mu = szf * fminf(fmaxf(__expf(gef * mu_) - 1.f, 1e-5f), 1e6f);
            out[e] = mu; out[(size_t)E + e] = disp; out[(size_t)2*E + e] = pi;
        }
    }
}

extern "C" void kernel_launch(void* const* d_in, const int* in_sizes, int n_in,
                              void* d_out, int out_size, void* d_ws, size_t ws_size,
                              hipStream_t stream) {
    const float* ufeats    = (const float*)d_in[0];
    const float* ifeats    = (const float*)d_in[1];
    const float* ge_factor = (const float*)d_in[2];
    const float* sz_factor = (const float*)d_in[3];
    const float* W_mean    = (const float*)d_in[4];
    const float* b_mean    = (const float*)d_in[5];
    const float* W_disp    = (const float*)d_in[6];
    const float* b_disp    = (const float*)d_in[7];
    const float* W_pi      = (const float*)d_in[8];
    const float* b_pi      = (const float*)d_in[9];
    const int*   src_idx   = (const int*)d_in[10];
    const int*   dst_idx   = (const int*)d_in[11];
    float* out = (float*)d_out;

    const int E       = in_sizes[10];
    const int n_cells = in_sizes[0] / 128;
    const int n_genes = in_sizes[1] / 128;

    const size_t u_elems = (size_t)n_cells * 128;
    const size_t i_elems = (size_t)n_genes * 128;
    const size_t ws_needed = (u_elems + i_elems) * sizeof(_Float16);

    if (ws_size >= ws_needed) {
        _Float16* uhalf = (_Float16*)d_ws;
        _Float16* ihalf = uhalf + u_elems;

        const int un4 = (int)(u_elems / 4);
        const int in4 = (int)(i_elems / 4);
        const int n4  = un4 + in4;
        hipLaunchKernelGGL(cvt_f16_fused_kernel, dim3((n4 + 255) / 256), dim3(256), 0, stream,
                           (const float4*)ufeats, un4, (const float4*)ifeats, in4,
                           (uint2*)d_ws);

        hipLaunchKernelGGL(zinb_mfma64_kernel, dim3(2048), dim3(256), 0, stream,
                           uhalf, ihalf, ge_factor, sz_factor,
                           W_mean, b_mean, W_disp, b_disp, W_pi, b_pi,
                           src_idx, dst_idx, out, E);

        const int rem = E & 63;
        if (rem) {
            hipLaunchKernelGGL(zinb_tail_kernel, dim3(1), dim3(64), 0, stream,
                               ufeats, ifeats, ge_factor, sz_factor,
                               W_mean, b_mean, W_disp, b_disp, W_pi, b_pi,
                               src_idx, dst_idx, out, E, E - rem);
        }
    } else {
        hipLaunchKernelGGL(zinb_edge_f32_kernel, dim3(2048), dim3(256), 0, stream,
                           ufeats, ifeats, ge_factor, sz_factor,
                           W_mean, b_mean, W_disp, b_disp, W_pi, b_pi,
                           src_idx, dst_idx, out, E);
    }
}

// Round 7
// 139.979 us; speedup vs baseline: 1.6510x; 1.0225x over previous
//
#include <hip/hip_runtime.h>
#include <math.h>

// R11 = R6 revert (measured session best: edge 61.5us, total 140.5us).
// Roofline witness: R5 (fdot2/8-lane, VALU 37%), R6 (fdot2/16-lane, VALU 52%),
// R10 (MFMA+LDS, VALU 22%) all land at 62+-2us moving the same 1.02GB of
// L2-resident gathers => ~16.6 TB/s effective random-gather service
// (~48% of the 4.3 TB/s/XCD sequential L2 rate). Pattern is already minimal:
// 4x128B line-touches/edge, f16, coalesced 256B-row reads. Traffic-reduction
// alternatives (cell-sort + scatter, dense GEMM at 10% density, fp8) are each
// net-negative or fail the accuracy budget. Remaining ~78us of dur_us is
// harness-fixed (constant across all 10 rounds, kernel-independent).

typedef _Float16 h2 __attribute__((ext_vector_type(2)));
union U16 { uint4 u; h2 h[4]; };
union HU { uint u; h2 h; };

// ---------- fused conversion kernel: both tables f32 -> f16 ------------------
__global__ __launch_bounds__(256) void cvt_f16_fused_kernel(
    const float4* __restrict__ srcA, int nA4,
    const float4* __restrict__ srcB, int nB4,
    uint2* __restrict__ dst)
{
    int i = blockIdx.x * blockDim.x + threadIdx.x;
    if (i >= nA4 + nB4) return;
    float4 f = (i < nA4) ? srcA[i] : srcB[i - nA4];
    HU a, b;
    a.h = h2{(_Float16)f.x, (_Float16)f.y};
    b.h = h2{(_Float16)f.z, (_Float16)f.w};
    dst[i] = make_uint2(a.u, b.u);
}

// one transpose-reduce stage: lane r accumulates toward edge bit `mask`
__device__ __forceinline__ float foldx(float a, float b, int mask, int r)
{
    const bool hi = (r & mask) != 0;
    const float keep = hi ? b : a;
    const float send = hi ? a : b;
    return keep + __shfl_xor(send, mask, 16);
}

// 12 fdot2 + 4 pk_mul for one edge's 8 elements held by this lane.
__device__ __forceinline__ void dot16(
    const U16& u, const U16& v,
    const h2* __restrict__ wm, const h2* __restrict__ wd, const h2* __restrict__ wp,
    float& m, float& dd, float& pp)
{
#pragma unroll
    for (int jj = 0; jj < 4; ++jj) {
        h2 q = u.h[jj] * v.h[jj];
        m  = __builtin_amdgcn_fdot2(q, wm[jj], m,  false);
        dd = __builtin_amdgcn_fdot2(q, wd[jj], dd, false);
        pp = __builtin_amdgcn_fdot2(q, wp[jj], pp, false);
    }
}

// broadcast lane J's value within each 16-lane group (BitMode swizzle:
// src_lane = (lane & 0x10) | J, compile-time immediate, no addr VALU)
#define SWZB(X, J) __builtin_amdgcn_ds_swizzle((X), 0x10 | ((J) << 5))

// fetch edge J's feature slices for this lane (16 B of u-row, 16 B of v-row)
#define PREF(J, U, V) {                                                   \
    const int su_ = SWZB(se, J);                                          \
    const int sg_ = SWZB(de, J);                                          \
    (U).u = *((const uint4*)(uhalf + (size_t)su_ * 128) + r);             \
    (V).u = *((const uint4*)(ihalf + (size_t)sg_ * 128) + r); }

// ---------- main edge kernel -------------------------------------------------
__global__ __launch_bounds__(256, 8) void zinb_edge16_kernel(
    const _Float16* __restrict__ uhalf,   // [n_cells, 128]
    const _Float16* __restrict__ ihalf,   // [n_genes, 128]
    const float* __restrict__ ge_factor,
    const float* __restrict__ sz_factor,
    const float* __restrict__ W_mean, const float* __restrict__ b_mean,
    const float* __restrict__ W_disp, const float* __restrict__ b_disp,
    const float* __restrict__ W_pi,   const float* __restrict__ b_pi,
    const int* __restrict__ src_idx,
    const int* __restrict__ dst_idx,
    float* __restrict__ out,              // [3E]: mu | disp | pi
    int E)
{
    const int tid = threadIdx.x;
    const int r = tid & 15;
    const int slot = (blockIdx.x * blockDim.x + tid) >> 4;
    const int n_slots = (gridDim.x * blockDim.x) >> 4;
    const int nmac = E >> 4;

    // lane r owns elems [r*8, r*8+8): 12 weight VGPRs total
    h2 wm[4], wd[4], wp[4];
    {
        const float4* a = (const float4*)W_mean + r * 2;
        const float4* b = (const float4*)W_disp + r * 2;
        const float4* c = (const float4*)W_pi   + r * 2;
        float4 a0 = a[0], a1 = a[1];
        float4 b0 = b[0], b1 = b[1];
        float4 c0 = c[0], c1 = c[1];
        wm[0] = h2{(_Float16)a0.x, (_Float16)a0.y}; wm[1] = h2{(_Float16)a0.z, (_Float16)a0.w};
        wm[2] = h2{(_Float16)a1.x, (_Float16)a1.y}; wm[3] = h2{(_Float16)a1.z, (_Float16)a1.w};
        wd[0] = h2{(_Float16)b0.x, (_Float16)b0.y}; wd[1] = h2{(_Float16)b0.z, (_Float16)b0.w};
        wd[2] = h2{(_Float16)b1.x, (_Float16)b1.y}; wd[3] = h2{(_Float16)b1.z, (_Float16)b1.w};
        wp[0] = h2{(_Float16)c0.x, (_Float16)c0.y}; wp[1] = h2{(_Float16)c0.z, (_Float16)c0.w};
        wp[2] = h2{(_Float16)c1.x, (_Float16)c1.y}; wp[3] = h2{(_Float16)c1.z, (_Float16)c1.w};
    }
    const float bm = b_mean[0], bd = b_disp[0], bp = b_pi[0];

    // prologue: per-lane own-edge indices for the first iteration
    int se = 0, de = 0;
    if (slot < nmac) {
        se = src_idx[(slot << 4) + r];
        de = dst_idx[(slot << 4) + r];
    }

    for (int q = slot; q < nmac; q += n_slots) {
        const int e0 = q << 4;
        const float szf = sz_factor[se];   // own-edge factor gathers (L1-hot)
        const float gef = ge_factor[de];

        U16 xu, xv, yu, yv;                // ping-pong: even edges x, odd y
        PREF(0, xu, xv)
        PREF(1, yu, yv)

        // cross-iteration index prefetch (hides idx->gather chain of next q)
        const int qn = q + n_slots;
        const int en0 = ((qn < nmac) ? qn : q) << 4;
        const int se_n = src_idx[en0 + r];
        const int de_n = dst_idx[en0 + r];

        float Hm0, Hd0, Hp0;
        {
            float Am, Ad, Ap;              // edges 0..3
            {
                float m0 = 0.f, d0 = 0.f, p0 = 0.f;
                dot16(xu, xv, wm, wd, wp, m0, d0, p0); PREF(2, xu, xv)
                float m1 = 0.f, d1 = 0.f, p1 = 0.f;
                dot16(yu, yv, wm, wd, wp, m1, d1, p1); PREF(3, yu, yv)
                const float t0m = foldx(m0, m1, 1, r);
                const float t0d = foldx(d0, d1, 1, r);
                const float t0p = foldx(p0, p1, 1, r);
                float m2 = 0.f, d2 = 0.f, p2 = 0.f;
                dot16(xu, xv, wm, wd, wp, m2, d2, p2); PREF(4, xu, xv)
                float m3 = 0.f, d3 = 0.f, p3 = 0.f;
                dot16(yu, yv, wm, wd, wp, m3, d3, p3); PREF(5, yu, yv)
                const float t1m = foldx(m2, m3, 1, r);
                const float t1d = foldx(d2, d3, 1, r);
                const float t1p = foldx(p2, p3, 1, r);
                Am = foldx(t0m, t1m, 2, r);
                Ad = foldx(t0d, t1d, 2, r);
                Ap = foldx(t0p, t1p, 2, r);
            }
            float Bm, Bd, Bp;              // edges 4..7
            {
                float m0 = 0.f, d0 = 0.f, p0 = 0.f;
                dot16(xu, xv, wm, wd, wp, m0, d0, p0); PREF(6, xu, xv)
                float m1 = 0.f, d1 = 0.f, p1 = 0.f;
                dot16(yu, yv, wm, wd, wp, m1, d1, p1); PREF(7, yu, yv)
                const float t0m = foldx(m0, m1, 1, r);
                const float t0d = foldx(d0, d1, 1, r);
                const float t0p = foldx(p0, p1, 1, r);
                float m2 = 0.f, d2 = 0.f, p2 = 0.f;
                dot16(xu, xv, wm, wd, wp, m2, d2, p2); PREF(8, xu, xv)
                float m3 = 0.f, d3 = 0.f, p3 = 0.f;
                dot16(yu, yv, wm, wd, wp, m3, d3, p3); PREF(9, yu, yv)
                const float t1m = foldx(m2, m3, 1, r);
                const float t1d = foldx(d2, d3, 1, r);
                const float t1p = foldx(p2, p3, 1, r);
                Bm = foldx(t0m, t1m, 2, r);
                Bd = foldx(t0d, t1d, 2, r);
                Bp = foldx(t0p, t1p, 2, r);
            }
            Hm0 = foldx(Am, Bm, 4, r);
            Hd0 = foldx(Ad, Bd, 4, r);
            Hp0 = foldx(Ap, Bp, 4, r);
        }
        float Hm1, Hd1, Hp1;
        {
            float Cm, Cd, Cp;              // edges 8..11
            {
                float m0 = 0.f, d0 = 0.f, p0 = 0.f;
                dot16(xu, xv, wm, wd, wp, m0, d0, p0); PREF(10, xu, xv)
                float m1 = 0.f, d1 = 0.f, p1 = 0.f;
                dot16(yu, yv, wm, wd, wp, m1, d1, p1); PREF(11, yu, yv)
                const float t0m = foldx(m0, m1, 1, r);
                const float t0d = foldx(d0, d1, 1, r);
                const float t0p = foldx(p0, p1, 1, r);
                float m2 = 0.f, d2 = 0.f, p2 = 0.f;
                dot16(xu, xv, wm, wd, wp, m2, d2, p2); PREF(12, xu, xv)
                float m3 = 0.f, d3 = 0.f, p3 = 0.f;
                dot16(yu, yv, wm, wd, wp, m3, d3, p3); PREF(13, yu, yv)
                const float t1m = foldx(m2, m3, 1, r);
                const float t1d = foldx(d2, d3, 1, r);
                const float t1p = foldx(p2, p3, 1, r);
                Cm = foldx(t0m, t1m, 2, r);
                Cd = foldx(t0d, t1d, 2, r);
                Cp = foldx(t0p, t1p, 2, r);
            }
            float Dm, Dd, Dp;              // edges 12..15
            {
                float m0 = 0.f, d0 = 0.f, p0 = 0.f;
                dot16(xu, xv, wm, wd, wp, m0, d0, p0); PREF(14, xu, xv)
                float m1 = 0.f, d1 = 0.f, p1 = 0.f;
                dot16(yu, yv, wm, wd, wp, m1, d1, p1); PREF(15, yu, yv)
                const float t0m = foldx(m0, m1, 1, r);
                const float t0d = foldx(d0, d1, 1, r);
                const float t0p = foldx(p0, p1, 1, r);
                float m2 = 0.f, d2 = 0.f, p2 = 0.f;
                dot16(xu, xv, wm, wd, wp, m2, d2, p2);
                float m3 = 0.f, d3 = 0.f, p3 = 0.f;
                dot16(yu, yv, wm, wd, wp, m3, d3, p3);
                const float t1m = foldx(m2, m3, 1, r);
                const float t1d = foldx(d2, d3, 1, r);
                const float t1p = foldx(p2, p3, 1, r);
                Dm = foldx(t0m, t1m, 2, r);
                Dd = foldx(t0d, t1d, 2, r);
                Dp = foldx(t0p, t1p, 2, r);
            }
            Hm1 = foldx(Cm, Dm, 4, r);
            Hd1 = foldx(Cd, Dd, 4, r);
            Hp1 = foldx(Cp, Dp, 4, r);
        }
        const float Fm = foldx(Hm0, Hm1, 8, r);
        const float Fd = foldx(Hd0, Hd1, 8, r);
        const float Fp = foldx(Hp0, Hp1, 8, r);

        // full-wave epilogue (lane r = edge e0 + r)
        const float mu_ = 1.f / (1.f + __expf(-(Fm + bm)));
        const float pi  = 1.f / (1.f + __expf(-(Fp + bp)));
        const float xd  = gef * (Fd + bd);
        const float sp  = fmaxf(xd, 0.f) + __logf(1.f + __expf(-fabsf(xd)));
        const float disp = fminf(fmaxf(sp, 1e-4f), 1e4f);
        const float mu = szf * fminf(fmaxf(__expf(gef * mu_) - 1.f, 1e-5f), 1e6f);

        const int e = e0 + r;
        out[e]                 = mu;
        out[(size_t)E + e]     = disp;
        out[(size_t)2 * E + e] = pi;

        se = se_n; de = de_n;
    }
}

// ---------- tail kernel: last E%16 edges, scalar f32 -------------------------
__global__ void zinb_tail_kernel(
    const float* __restrict__ ufeats, const float* __restrict__ ifeats,
    const float* __restrict__ ge_factor, const float* __restrict__ sz_factor,
    const float* __restrict__ W_mean, const float* __restrict__ b_mean,
    const float* __restrict__ W_disp, const float* __restrict__ b_disp,
    const float* __restrict__ W_pi,   const float* __restrict__ b_pi,
    const int* __restrict__ src_idx, const int* __restrict__ dst_idx,
    float* __restrict__ out, int E, int start)
{
    int e = start + blockIdx.x * blockDim.x + threadIdx.x;
    if (e >= E) return;
    const int s = src_idx[e], g = dst_idx[e];
    float am = 0.f, ad = 0.f, ap = 0.f;
    for (int k = 0; k < 128; ++k) {
        float h = ufeats[(size_t)s * 128 + k] * ifeats[(size_t)g * 128 + k];
        am = fmaf(h, W_mean[k], am);
        ad = fmaf(h, W_disp[k], ad);
        ap = fmaf(h, W_pi[k],   ap);
    }
    const float gef = ge_factor[g];
    const float szf = sz_factor[s];
    const float mu_ = 1.f / (1.f + __expf(-(am + b_mean[0])));
    const float pi  = 1.f / (1.f + __expf(-(ap + b_pi[0])));
    const float xd  = gef * (ad + b_disp[0]);
    const float sp  = fmaxf(xd, 0.f) + __logf(1.f + __expf(-fabsf(xd)));
    const float disp = fminf(fmaxf(sp, 1e-4f), 1e4f);
    const float mu = szf * fminf(fmaxf(__expf(gef * mu_) - 1.f, 1e-5f), 1e6f);
    out[e] = mu; out[(size_t)E + e] = disp; out[(size_t)2 * E + e] = pi;
}

// ---------- fallback: pure-f32 kernel (ws too small) -------------------------
__global__ __launch_bounds__(256) void zinb_edge_f32_kernel(
    const float* __restrict__ ufeats, const float* __restrict__ ifeats,
    const float* __restrict__ ge_factor, const float* __restrict__ sz_factor,
    const float* __restrict__ W_mean, const float* __restrict__ b_mean,
    const float* __restrict__ W_disp, const float* __restrict__ b_disp,
    const float* __restrict__ W_pi,   const float* __restrict__ b_pi,
    const int* __restrict__ src_idx, const int* __restrict__ dst_idx,
    float* __restrict__ out, int E)
{
    const int r = threadIdx.x & 7;
    const int slot = (blockIdx.x * blockDim.x + threadIdx.x) >> 3;
    const int n_slots = (gridDim.x * blockDim.x) >> 3;

    float4 wm[4], wd[4], wp[4];
    {
        const float4* wm4 = (const float4*)W_mean + r;
        const float4* wd4 = (const float4*)W_disp + r;
        const float4* wp4 = (const float4*)W_pi   + r;
#pragma unroll
        for (int c = 0; c < 4; ++c) { wm[c] = wm4[c*8]; wd[c] = wd4[c*8]; wp[c] = wp4[c*8]; }
    }
    const float bm = b_mean[0], bd = b_disp[0], bp = b_pi[0];

    for (int e = slot; e < E; e += n_slots) {
        const int s = src_idx[e];
        const int g = dst_idx[e];
        const float4* u4 = (const float4*)(ufeats + (size_t)s * 128) + r;
        const float4* v4 = (const float4*)(ifeats + (size_t)g * 128) + r;
        float am = 0.f, ad = 0.f, ap = 0.f;
#pragma unroll
        for (int c = 0; c < 4; ++c) {
            float4 u = u4[c*8]; float4 v = v4[c*8];
            float px = u.x*v.x, py = u.y*v.y, pz = u.z*v.z, pw = u.w*v.w;
            am = fmaf(px, wm[c].x, am); am = fmaf(py, wm[c].y, am);
            am = fmaf(pz, wm[c].z, am); am = fmaf(pw, wm[c].w, am);
            ad = fmaf(px, wd[c].x, ad); ad = fmaf(py, wd[c].y, ad);
            ad = fmaf(pz, wd[c].z, ad); ad = fmaf(pw, wd[c].w, ad);
            ap = fmaf(px, wp[c].x, ap); ap = fmaf(py, wp[c].y, ap);
            ap = fmaf(pz, wp[c].z, ap); ap = fmaf(pw, wp[c].w, ap);
        }
#pragma unroll
        for (int off = 1; off < 8; off <<= 1) {
            am += __shfl_xor(am, off); ad += __shfl_xor(ad, off); ap += __shfl_xor(ap, off);
        }
        if (r == 0) {
            const float gef = ge_factor[g];
            const float szf = sz_factor[s];
            const float mu_ = 1.f / (1.f + __expf(-(am + bm)));
            const float pi  = 1.f / (1.f + __expf(-(ap + bp)));
            const float xd  = gef * (ad + bd);
            const float sp  = fmaxf(xd, 0.f) + __logf(1.f + __expf(-fabsf(xd)));
            const float disp = fminf(fmaxf(sp, 1e-4f), 1e4f);
            const float mu = szf * fminf(fmaxf(__expf(gef * mu_) - 1.f, 1e-5f), 1e6f);
            out[e] = mu; out[(size_t)E + e] = disp; out[(size_t)2*E + e] = pi;
        }
    }
}

extern "C" void kernel_launch(void* const* d_in, const int* in_sizes, int n_in,
                              void* d_out, int out_size, void* d_ws, size_t ws_size,
                              hipStream_t stream) {
    const float* ufeats    = (const float*)d_in[0];
    const float* ifeats    = (const float*)d_in[1];
    const float* ge_factor = (const float*)d_in[2];
    const float* sz_factor = (const float*)d_in[3];
    const float* W_mean    = (const float*)d_in[4];
    const float* b_mean    = (const float*)d_in[5];
    const float* W_disp    = (const float*)d_in[6];
    const float* b_disp    = (const float*)d_in[7];
    const float* W_pi      = (const float*)d_in[8];
    const float* b_pi      = (const float*)d_in[9];
    const int*   src_idx   = (const int*)d_in[10];
    const int*   dst_idx   = (const int*)d_in[11];
    float* out = (float*)d_out;

    const int E       = in_sizes[10];
    const int n_cells = in_sizes[0] / 128;
    const int n_genes = in_sizes[1] / 128;

    const size_t u_elems = (size_t)n_cells * 128;
    const size_t i_elems = (size_t)n_genes * 128;
    const size_t ws_needed = (u_elems + i_elems) * sizeof(_Float16);

    if (ws_size >= ws_needed) {
        _Float16* uhalf = (_Float16*)d_ws;
        _Float16* ihalf = uhalf + u_elems;

        const int un4 = (int)(u_elems / 4);
        const int in4 = (int)(i_elems / 4);
        const int n4  = un4 + in4;
        hipLaunchKernelGGL(cvt_f16_fused_kernel, dim3((n4 + 255) / 256), dim3(256), 0, stream,
                           (const float4*)ufeats, un4, (const float4*)ifeats, in4,
                           (uint2*)d_ws);

        hipLaunchKernelGGL(zinb_edge16_kernel, dim3(2048), dim3(256), 0, stream,
                           uhalf, ihalf, ge_factor, sz_factor,
                           W_mean, b_mean, W_disp, b_disp, W_pi, b_pi,
                           src_idx, dst_idx, out, E);

        const int rem = E & 15;
        if (rem) {
            hipLaunchKernelGGL(zinb_tail_kernel, dim3(1), dim3(64), 0, stream,
                               ufeats, ifeats, ge_factor, sz_factor,
                               W_mean, b_mean, W_disp, b_disp, W_pi, b_pi,
                               src_idx, dst_idx, out, E, E - rem);
        }
    } else {
        hipLaunchKernelGGL(zinb_edge_f32_kernel, dim3(2048), dim3(256), 0, stream,
                           ufeats, ifeats, ge_factor, sz_factor,
                           W_mean, b_mean, W_disp, b_disp, W_pi, b_pi,
                           src_idx, dst_idx, out, E);
    }
}